// Round 1
// baseline (4333.323 us; speedup 1.0000x reference)
//
#include <hip/hip_runtime.h>
#include <math.h>

#define T_ 32
#define B_ 32
#define S_ 200
#define E_ 512
#define H_ 512
#define V_ 50000
#define G4_ 2048
#define NCH 196   // ceil(50000/256)

__device__ __forceinline__ float sigf(float x) { return 1.f / (1.f + expf(-x)); }

// ---------------------------------------------------------------------------
// Kernel A: G0[m][j] = emb(tgt_in[m]) . W_ih[j][0:512] + b_ih[j] + b_hh[j]
// m = t*B+b (1024 rows), j (2048). Tiled GEMM BM=64 BN=128 BK=32, micro 8x4.
// ---------------------------------------------------------------------------
__global__ __launch_bounds__(256) void k_g0(const int* __restrict__ tgt_in,
                                            const float* __restrict__ emb,
                                            const float* __restrict__ Wih,
                                            const float* __restrict__ bih,
                                            const float* __restrict__ bhh,
                                            float* __restrict__ G0) {
    __shared__ float a_s[32][66];
    __shared__ float w_s[32][130];
    const int tid = threadIdx.x;
    const int m0 = blockIdx.x * 64, n0 = blockIdx.y * 128;
    const int mq = tid >> 5, nq = tid & 31;
    float acc[8][4] = {};
    for (int k0 = 0; k0 < 512; k0 += 32) {
        {   // A tile 64x32 (gathered embedding rows), store k-major
            const int mm = tid >> 2, kq = tid & 3, kk = kq * 8;
            const float* row = emb + (size_t)tgt_in[m0 + mm] * E_ + k0 + kk;
            float4 v0 = *(const float4*)(row);
            float4 v1 = *(const float4*)(row + 4);
            a_s[kk + 0][mm] = v0.x; a_s[kk + 1][mm] = v0.y;
            a_s[kk + 2][mm] = v0.z; a_s[kk + 3][mm] = v0.w;
            a_s[kk + 4][mm] = v1.x; a_s[kk + 5][mm] = v1.y;
            a_s[kk + 6][mm] = v1.z; a_s[kk + 7][mm] = v1.w;
        }
        {   // W tile 128x32 (W_ih row stride 1024), store k-major
            const int nn = tid >> 1, kq = tid & 1, kk = kq * 16;
            const float* row = Wih + (size_t)(n0 + nn) * 1024 + k0 + kk;
            #pragma unroll
            for (int u = 0; u < 4; u++) {
                float4 v = *(const float4*)(row + u * 4);
                w_s[kk + u * 4 + 0][nn] = v.x; w_s[kk + u * 4 + 1][nn] = v.y;
                w_s[kk + u * 4 + 2][nn] = v.z; w_s[kk + u * 4 + 3][nn] = v.w;
            }
        }
        __syncthreads();
        for (int k = 0; k < 32; k++) {
            float a[8], wv[4];
            #pragma unroll
            for (int i = 0; i < 8; i++) a[i] = a_s[k][mq + 8 * i];
            #pragma unroll
            for (int p = 0; p < 4; p++) wv[p] = w_s[k][nq + 32 * p];
            #pragma unroll
            for (int i = 0; i < 8; i++)
                #pragma unroll
                for (int p = 0; p < 4; p++) acc[i][p] += a[i] * wv[p];
        }
        __syncthreads();
    }
    #pragma unroll
    for (int i = 0; i < 8; i++) {
        const int m = m0 + mq + 8 * i;
        #pragma unroll
        for (int p = 0; p < 4; p++) {
            const int n = n0 + nq + 32 * p;
            G0[(size_t)m * G4_ + n] = acc[i][p] + bih[n] + bhh[n];
        }
    }
}

// ---------------------------------------------------------------------------
// Kernel P1 (per step t): distributed-row GEMMs.
//  - dec(t-1) = tanh([emb,h,att] @ W_gen^T + b_gen)   (512 rows over 256 blocks)
//  - gates(t) = G0[t] + att @ W_ih[:,E:]^T + h @ W_hh^T (2048 rows over 256 blocks)
// Each wave: lane = half*32 + b; K split across halves; shfl_xor(32) combine.
// ---------------------------------------------------------------------------
__global__ __launch_bounds__(256) void k_step1(const float* __restrict__ G0,
                                               const float* __restrict__ Wih,
                                               const float* __restrict__ Whh,
                                               const float* __restrict__ Wgen,
                                               const float* __restrict__ bgen,
                                               const float* __restrict__ emb,
                                               const int* __restrict__ tgt_in,
                                               const float* __restrict__ hbuf,
                                               const float* __restrict__ attbuf,
                                               float* __restrict__ gates,
                                               float* __restrict__ decs,
                                               int t) {
    const int blk = blockIdx.x, tid = threadIdx.x;
    const int w = tid >> 6, lane = tid & 63, b = lane & 31, half = lane >> 5;
    const bool do_dec = (t > 0), do_gates = (t < T_);

    if (do_dec && w < 2) {
        const int dj = blk * 2 + w, tm1 = t - 1;
        const float* er = emb + (size_t)tgt_in[tm1 * B_ + b] * E_;
        const float* hr = hbuf + b * H_;
        const float* ar = attbuf + b * H_;
        const float* wr = Wgen + (size_t)dj * 1536;
        float a0 = 0, a1 = 0, a2 = 0, a3 = 0;
        const int lo = half * 768, hi = lo + 768;
        for (int k = lo; k < hi; k += 4) {
            const float* xp = (k < 512) ? (er + k) : (k < 1024) ? (hr + k - 512) : (ar + k - 1024);
            float4 x4 = *(const float4*)xp;
            float4 w4 = *(const float4*)(wr + k);
            a0 += x4.x * w4.x; a1 += x4.y * w4.y; a2 += x4.z * w4.z; a3 += x4.w * w4.w;
        }
        float acc = (a0 + a1) + (a2 + a3);
        acc += __shfl_xor(acc, 32);
        if (half == 0) decs[((size_t)tm1 * B_ + b) * H_ + dj] = tanhf(acc + bgen[dj]);
    }

    if (do_gates) {
        int rbeg, rend;
        if (do_dec) {
            if (w == 0)      { rbeg = 0; rend = 1; }
            else if (w == 1) { rbeg = 1; rend = 2; }
            else if (w == 2) { rbeg = 2; rend = 5; }
            else             { rbeg = 5; rend = 8; }
        } else { rbeg = 2 * w; rend = rbeg + 2; }
        const float* xr = (half == 0) ? (attbuf + b * H_) : (hbuf + b * H_);
        for (int r = rbeg; r < rend; r++) {
            const int j = blk * 8 + r;
            const float* wr = (half == 0) ? (Wih + (size_t)j * 1024 + 512)
                                          : (Whh + (size_t)j * 512);
            float a0 = 0, a1 = 0, a2 = 0, a3 = 0;
            #pragma unroll 4
            for (int k = 0; k < 512; k += 4) {
                float4 x4 = *(const float4*)(xr + k);
                float4 w4 = *(const float4*)(wr + k);
                a0 += x4.x * w4.x; a1 += x4.y * w4.y; a2 += x4.z * w4.z; a3 += x4.w * w4.w;
            }
            float acc = (a0 + a1) + (a2 + a3);
            acc += __shfl_xor(acc, 32);
            if (half == 0)
                gates[b * G4_ + j] = acc + G0[((size_t)t * B_ + b) * G4_ + j];
        }
    }
}

// ---------------------------------------------------------------------------
// Kernel P2 (per step): per-b block: LSTM pointwise + scores + softmax + ctx.
// ---------------------------------------------------------------------------
__global__ __launch_bounds__(512) void k_step2(const float* __restrict__ gates,
                                               float* __restrict__ cbuf,
                                               float* __restrict__ hbuf,
                                               const float* __restrict__ src,
                                               const int* __restrict__ lens,
                                               float* __restrict__ ctxbuf) {
    const int b = blockIdx.x, tid = threadIdx.x;
    __shared__ float h_s[H_];
    __shared__ float sc[256];
    if (tid < H_) {
        const float gi = gates[b * G4_ + tid];
        const float gf = gates[b * G4_ + H_ + tid];
        const float gg = gates[b * G4_ + 2 * H_ + tid];
        const float go = gates[b * G4_ + 3 * H_ + tid];
        const float co = cbuf[b * H_ + tid];
        const float cn = sigf(gf) * co + sigf(gi) * tanhf(gg);
        const float hn = sigf(go) * tanhf(cn);
        cbuf[b * H_ + tid] = cn;
        hbuf[b * H_ + tid] = hn;
        h_s[tid] = hn;
    }
    __syncthreads();
    const int w = tid >> 6, lane = tid & 63;
    const int len = lens[b];
    for (int s = w; s < S_; s += 8) {
        const float* sr = src + ((size_t)b * S_ + s) * H_;
        float4 x0 = *(const float4*)(sr + lane * 4);
        float4 h0 = *(const float4*)(&h_s[lane * 4]);
        float4 x1 = *(const float4*)(sr + 256 + lane * 4);
        float4 h1 = *(const float4*)(&h_s[256 + lane * 4]);
        float acc = x0.x * h0.x + x0.y * h0.y + x0.z * h0.z + x0.w * h0.w
                  + x1.x * h1.x + x1.y * h1.y + x1.z * h1.z + x1.w * h1.w;
        #pragma unroll
        for (int m = 1; m < 64; m <<= 1) acc += __shfl_xor(acc, m);
        if (lane == 0) sc[s] = (s < len) ? acc : -INFINITY;
    }
    __syncthreads();
    if (tid < 64) {  // softmax over 200, wave 0
        const int s0 = tid, s1 = tid + 64, s2 = tid + 128, s3 = tid + 192;
        const float v0 = sc[s0], v1 = sc[s1], v2 = sc[s2];
        const float v3 = (s3 < S_) ? sc[s3] : -INFINITY;
        float m = fmaxf(fmaxf(v0, v1), fmaxf(v2, v3));
        #pragma unroll
        for (int mk = 1; mk < 64; mk <<= 1) m = fmaxf(m, __shfl_xor(m, mk));
        const float e0 = expf(v0 - m), e1 = expf(v1 - m), e2 = expf(v2 - m);
        const float e3 = (s3 < S_) ? expf(v3 - m) : 0.f;
        float sum = (e0 + e1) + (e2 + e3);
        #pragma unroll
        for (int mk = 1; mk < 64; mk <<= 1) sum += __shfl_xor(sum, mk);
        const float inv = 1.f / sum;
        sc[s0] = e0 * inv; sc[s1] = e1 * inv; sc[s2] = e2 * inv;
        if (s3 < S_) sc[s3] = e3 * inv;
    }
    __syncthreads();
    if (tid < H_) {  // ctx
        const float* sp = src + (size_t)b * S_ * H_ + tid;
        float a0 = 0, a1 = 0, a2 = 0, a3 = 0;
        for (int s = 0; s < S_; s += 4) {
            a0 += sc[s] * sp[(s) * H_];
            a1 += sc[s + 1] * sp[(s + 1) * H_];
            a2 += sc[s + 2] * sp[(s + 2) * H_];
            a3 += sc[s + 3] * sp[(s + 3) * H_];
        }
        ctxbuf[b * H_ + tid] = (a0 + a1) + (a2 + a3);
    }
}

// ---------------------------------------------------------------------------
// Kernel P3 (per step): att = tanh([ctx,h] @ W_attn^T), 512 rows over 64 blocks.
// ---------------------------------------------------------------------------
__global__ __launch_bounds__(256) void k_step3(const float* __restrict__ Wattn,
                                               const float* __restrict__ ctxbuf,
                                               const float* __restrict__ hbuf,
                                               float* __restrict__ attbuf) {
    const int blk = blockIdx.x, tid = threadIdx.x;
    const int w = tid >> 6, lane = tid & 63, b = lane & 31, half = lane >> 5;
    const float* xr = (half == 0) ? (ctxbuf + b * H_) : (hbuf + b * H_);
    #pragma unroll
    for (int r = 0; r < 2; r++) {
        const int j = blk * 8 + w * 2 + r;
        const float* wr = Wattn + (size_t)j * 1024 + half * 512;
        float a0 = 0, a1 = 0, a2 = 0, a3 = 0;
        #pragma unroll 4
        for (int k = 0; k < 512; k += 4) {
            float4 x4 = *(const float4*)(xr + k);
            float4 w4 = *(const float4*)(wr + k);
            a0 += x4.x * w4.x; a1 += x4.y * w4.y; a2 += x4.z * w4.z; a3 += x4.w * w4.w;
        }
        float acc = (a0 + a1) + (a2 + a3);
        acc += __shfl_xor(acc, 32);
        if (half == 0) attbuf[b * H_ + j] = tanhf(acc);
    }
}

// ---------------------------------------------------------------------------
// Kernel C: readout GEMM partials. Per block: 64 rows x 256-col chunk, K=512.
// Emits per (row,chunk): {max, sumexp(rel max), argmax}, plus tgt logit.
// ---------------------------------------------------------------------------
__global__ __launch_bounds__(256) void k_read(const float* __restrict__ decs,
                                              const float* __restrict__ Wread,
                                              const int* __restrict__ tgt_out,
                                              float4* __restrict__ part,
                                              float* __restrict__ tgt_logit) {
    __shared__ float a_s[32][66];
    __shared__ float w_s[32][258];
    const int tid = threadIdx.x;
    const int m0 = blockIdx.x * 64;
    const int ch = blockIdx.y;
    const int n0 = ch * 256;
    const int mq = tid >> 5, nq = tid & 31;
    float acc[8][8] = {};
    for (int k0 = 0; k0 < 512; k0 += 32) {
        {
            const int mm = tid >> 2, kq = tid & 3, kk = kq * 8;
            const float* row = decs + (size_t)(m0 + mm) * H_ + k0 + kk;
            float4 v0 = *(const float4*)(row);
            float4 v1 = *(const float4*)(row + 4);
            a_s[kk + 0][mm] = v0.x; a_s[kk + 1][mm] = v0.y;
            a_s[kk + 2][mm] = v0.z; a_s[kk + 3][mm] = v0.w;
            a_s[kk + 4][mm] = v1.x; a_s[kk + 5][mm] = v1.y;
            a_s[kk + 6][mm] = v1.z; a_s[kk + 7][mm] = v1.w;
        }
        {
            const int nn = tid;
            const int n = n0 + nn;
            if (n < V_) {
                const float* row = Wread + (size_t)n * H_ + k0;
                #pragma unroll
                for (int u = 0; u < 8; u++) {
                    float4 v = *(const float4*)(row + u * 4);
                    w_s[u * 4 + 0][nn] = v.x; w_s[u * 4 + 1][nn] = v.y;
                    w_s[u * 4 + 2][nn] = v.z; w_s[u * 4 + 3][nn] = v.w;
                }
            } else {
                #pragma unroll
                for (int u = 0; u < 32; u++) w_s[u][nn] = 0.f;
            }
        }
        __syncthreads();
        for (int k = 0; k < 32; k++) {
            float a[8], wv[8];
            #pragma unroll
            for (int i = 0; i < 8; i++) a[i] = a_s[k][mq + 8 * i];
            #pragma unroll
            for (int j = 0; j < 8; j++) wv[j] = w_s[k][nq + 32 * j];
            #pragma unroll
            for (int i = 0; i < 8; i++)
                #pragma unroll
                for (int j = 0; j < 8; j++) acc[i][j] += a[i] * wv[j];
        }
        __syncthreads();
    }
    #pragma unroll
    for (int i = 0; i < 8; i++) {
        const int m = m0 + mq + 8 * i;
        float bv = -INFINITY; int bi = 0x7fffffff;
        #pragma unroll
        for (int j = 0; j < 8; j++) {
            const int n = n0 + nq + 32 * j;
            const float v = (n < V_) ? acc[i][j] : -INFINITY;
            if (v > bv || (v == bv && n < bi)) { bv = v; bi = n; }
        }
        #pragma unroll
        for (int mk = 1; mk < 32; mk <<= 1) {
            const float ov = __shfl_xor(bv, mk);
            const int oi = __shfl_xor(bi, mk);
            if (ov > bv || (ov == bv && oi < bi)) { bv = ov; bi = oi; }
        }
        float se = 0.f;
        #pragma unroll
        for (int j = 0; j < 8; j++) {
            const int n = n0 + nq + 32 * j;
            se += (n < V_) ? expf(acc[i][j] - bv) : 0.f;
        }
        #pragma unroll
        for (int mk = 1; mk < 32; mk <<= 1) se += __shfl_xor(se, mk);
        if (nq == 0) part[(size_t)m * NCH + ch] = make_float4(bv, se, __int_as_float(bi), 0.f);
        const int ct = tgt_out[m];
        const int rel = ct - n0;
        if (rel >= 0 && rel < 256 && (rel & 31) == nq) {
            #pragma unroll
            for (int j = 0; j < 8; j++)
                if (rel == nq + 32 * j) tgt_logit[m] = acc[i][j];
        }
    }
}

// ---------------------------------------------------------------------------
// Kernel D: merge chunk partials per row -> loss + argmax.
// ---------------------------------------------------------------------------
__global__ __launch_bounds__(256) void k_merge(const float4* __restrict__ part,
                                               const float* __restrict__ tgt_logit,
                                               const int* __restrict__ tgt_out,
                                               float* __restrict__ out) {
    const int tid = threadIdx.x;
    const int w = tid >> 6, lane = tid & 63;
    const int row = blockIdx.x * 4 + w;
    float bm = -INFINITY; int bi = 0x7fffffff;
    for (int ch = lane; ch < NCH; ch += 64) {
        const float4 p = part[(size_t)row * NCH + ch];
        const int pi = __float_as_int(p.z);
        if (p.x > bm || (p.x == bm && pi < bi)) { bm = p.x; bi = pi; }
    }
    #pragma unroll
    for (int mk = 1; mk < 64; mk <<= 1) {
        const float ov = __shfl_xor(bm, mk);
        const int oi = __shfl_xor(bi, mk);
        if (ov > bm || (ov == bm && oi < bi)) { bm = ov; bi = oi; }
    }
    float sum = 0.f;
    for (int ch = lane; ch < NCH; ch += 64) {
        const float4 p = part[(size_t)row * NCH + ch];
        sum += p.y * expf(p.x - bm);
    }
    #pragma unroll
    for (int mk = 1; mk < 64; mk <<= 1) sum += __shfl_xor(sum, mk);
    if (lane == 0) {
        const float lse = bm + logf(sum);
        const int tg = tgt_out[row];
        const float loss = (tg != 0) ? (lse - tgt_logit[row]) : 0.f;
        out[row] = loss;            // word_losses (T,B) flat
        out[1024 + row] = (float)bi; // ys (T,B) flat
    }
}

// ---------------------------------------------------------------------------
extern "C" void kernel_launch(void* const* d_in, const int* in_sizes, int n_in,
                              void* d_out, int out_size, void* d_ws, size_t ws_size,
                              hipStream_t stream) {
    const int* tgt_in = (const int*)d_in[0];
    const int* tgt_out = (const int*)d_in[1];
    const int* src_lens = (const int*)d_in[2];
    const float* src = (const float*)d_in[3];
    const float* last_state = (const float*)d_in[4];
    const float* last_cell = (const float*)d_in[5];
    const float* emb = (const float*)d_in[6];
    const float* Wih = (const float*)d_in[7];
    const float* Whh = (const float*)d_in[8];
    const float* bih = (const float*)d_in[9];
    const float* bhh = (const float*)d_in[10];
    const float* Wattn = (const float*)d_in[11];
    const float* Wgen = (const float*)d_in[12];
    const float* bgen = (const float*)d_in[13];
    const float* Wread = (const float*)d_in[14];
    float* out = (float*)d_out;

    float* ws = (float*)d_ws;
    float* G0 = ws;                       // 2,097,152 floats
    float* decs = G0 + 2097152;           // 524,288
    float* hbuf = decs + 524288;          // 16,384
    float* cbuf = hbuf + 16384;           // 16,384
    float* attbuf = cbuf + 16384;         // 16,384
    float* ctxbuf = attbuf + 16384;       // 16,384
    float* gates = ctxbuf + 16384;        // 65,536
    float4* part = (float4*)(gates + 65536); // 200,704 float4
    float* tgtl = ((float*)part) + 802816;   // 1,024

    hipMemcpyAsync(hbuf, last_state, (size_t)B_ * H_ * 4, hipMemcpyDeviceToDevice, stream);
    hipMemcpyAsync(cbuf, last_cell, (size_t)B_ * H_ * 4, hipMemcpyDeviceToDevice, stream);
    hipMemsetAsync(attbuf, 0, (size_t)B_ * H_ * 4, stream);

    k_g0<<<dim3(16, 16), 256, 0, stream>>>(tgt_in, emb, Wih, bih, bhh, G0);

    for (int t = 0; t <= T_; t++) {
        k_step1<<<256, 256, 0, stream>>>(G0, Wih, Whh, Wgen, bgen, emb, tgt_in,
                                         hbuf, attbuf, gates, decs, t);
        if (t < T_) {
            k_step2<<<32, 512, 0, stream>>>(gates, cbuf, hbuf, src, src_lens, ctxbuf);
            k_step3<<<64, 256, 0, stream>>>(Wattn, ctxbuf, hbuf, attbuf);
        }
    }

    k_read<<<dim3(16, NCH), 256, 0, stream>>>(decs, Wread, tgt_out, part, tgtl);
    k_merge<<<256, 256, 0, stream>>>(part, tgtl, tgt_out, out);
}

// Round 2
// 4328.493 us; speedup vs baseline: 1.0011x; 1.0011x over previous
//
#include <hip/hip_runtime.h>
#include <math.h>

#define T_ 32
#define B_ 32
#define S_ 200
#define E_ 512
#define H_ 512
#define V_ 50000
#define G4_ 2048
#define NCH 196   // ceil(50000/256)

__device__ __forceinline__ float sigf(float x) { return 1.f / (1.f + expf(-x)); }

// ---------------------------------------------------------------------------
// Manual grid barrier: monotonic counter, device-scope atomics. 256 blocks
// co-resident (1 block/CU on 256 CUs).
// ---------------------------------------------------------------------------
__device__ __forceinline__ void grid_sync(int* bar, int target) {
    __syncthreads();
    if (threadIdx.x == 0) {
        __threadfence();
        __hip_atomic_fetch_add(bar, 1, __ATOMIC_ACQ_REL, __HIP_MEMORY_SCOPE_AGENT);
        while (__hip_atomic_load(bar, __ATOMIC_ACQUIRE, __HIP_MEMORY_SCOPE_AGENT) < target) {
            __builtin_amdgcn_s_sleep(1);
        }
        __threadfence();
    }
    __syncthreads();
}

// ---------------------------------------------------------------------------
// Kernel A: G0[m][j] = emb(tgt_in[m]) . W_ih[j][0:512] + b_ih[j] + b_hh[j]
// ---------------------------------------------------------------------------
__global__ __launch_bounds__(256) void k_g0(const int* __restrict__ tgt_in,
                                            const float* __restrict__ emb,
                                            const float* __restrict__ Wih,
                                            const float* __restrict__ bih,
                                            const float* __restrict__ bhh,
                                            float* __restrict__ G0) {
    __shared__ float a_s[32][66];
    __shared__ float w_s[32][130];
    const int tid = threadIdx.x;
    const int m0 = blockIdx.x * 64, n0 = blockIdx.y * 128;
    const int mq = tid >> 5, nq = tid & 31;
    float acc[8][4] = {};
    for (int k0 = 0; k0 < 512; k0 += 32) {
        {
            const int mm = tid >> 2, kq = tid & 3, kk = kq * 8;
            const float* row = emb + (size_t)tgt_in[m0 + mm] * E_ + k0 + kk;
            float4 v0 = *(const float4*)(row);
            float4 v1 = *(const float4*)(row + 4);
            a_s[kk + 0][mm] = v0.x; a_s[kk + 1][mm] = v0.y;
            a_s[kk + 2][mm] = v0.z; a_s[kk + 3][mm] = v0.w;
            a_s[kk + 4][mm] = v1.x; a_s[kk + 5][mm] = v1.y;
            a_s[kk + 6][mm] = v1.z; a_s[kk + 7][mm] = v1.w;
        }
        {
            const int nn = tid >> 1, kq = tid & 1, kk = kq * 16;
            const float* row = Wih + (size_t)(n0 + nn) * 1024 + k0 + kk;
            #pragma unroll
            for (int u = 0; u < 4; u++) {
                float4 v = *(const float4*)(row + u * 4);
                w_s[kk + u * 4 + 0][nn] = v.x; w_s[kk + u * 4 + 1][nn] = v.y;
                w_s[kk + u * 4 + 2][nn] = v.z; w_s[kk + u * 4 + 3][nn] = v.w;
            }
        }
        __syncthreads();
        for (int k = 0; k < 32; k++) {
            float a[8], wv[4];
            #pragma unroll
            for (int i = 0; i < 8; i++) a[i] = a_s[k][mq + 8 * i];
            #pragma unroll
            for (int p = 0; p < 4; p++) wv[p] = w_s[k][nq + 32 * p];
            #pragma unroll
            for (int i = 0; i < 8; i++)
                #pragma unroll
                for (int p = 0; p < 4; p++) acc[i][p] += a[i] * wv[p];
        }
        __syncthreads();
    }
    #pragma unroll
    for (int i = 0; i < 8; i++) {
        const int m = m0 + mq + 8 * i;
        #pragma unroll
        for (int p = 0; p < 4; p++) {
            const int n = n0 + nq + 32 * p;
            G0[(size_t)m * G4_ + n] = acc[i][p] + bih[n] + bhh[n];
        }
    }
}

// ---------------------------------------------------------------------------
// Kernel U: U[b,s,j] = src[b,s,:] . W_attn[j, 0:512]   (M=6400,N=512,K=512)
// ---------------------------------------------------------------------------
__global__ __launch_bounds__(256) void k_u(const float* __restrict__ src,
                                           const float* __restrict__ Wattn,
                                           float* __restrict__ U) {
    __shared__ float a_s[32][66];
    __shared__ float w_s[32][130];
    const int tid = threadIdx.x;
    const int m0 = blockIdx.x * 64, n0 = blockIdx.y * 128;
    const int mq = tid >> 5, nq = tid & 31;
    float acc[8][4] = {};
    for (int k0 = 0; k0 < 512; k0 += 32) {
        {
            const int mm = tid >> 2, kq = tid & 3, kk = kq * 8;
            const float* row = src + (size_t)(m0 + mm) * 512 + k0 + kk;
            float4 v0 = *(const float4*)(row);
            float4 v1 = *(const float4*)(row + 4);
            a_s[kk + 0][mm] = v0.x; a_s[kk + 1][mm] = v0.y;
            a_s[kk + 2][mm] = v0.z; a_s[kk + 3][mm] = v0.w;
            a_s[kk + 4][mm] = v1.x; a_s[kk + 5][mm] = v1.y;
            a_s[kk + 6][mm] = v1.z; a_s[kk + 7][mm] = v1.w;
        }
        {
            const int nn = tid >> 1, kq = tid & 1, kk = kq * 16;
            const float* row = Wattn + (size_t)(n0 + nn) * 1024 + k0 + kk;
            #pragma unroll
            for (int u = 0; u < 4; u++) {
                float4 v = *(const float4*)(row + u * 4);
                w_s[kk + u * 4 + 0][nn] = v.x; w_s[kk + u * 4 + 1][nn] = v.y;
                w_s[kk + u * 4 + 2][nn] = v.z; w_s[kk + u * 4 + 3][nn] = v.w;
            }
        }
        __syncthreads();
        for (int k = 0; k < 32; k++) {
            float a[8], wv[4];
            #pragma unroll
            for (int i = 0; i < 8; i++) a[i] = a_s[k][mq + 8 * i];
            #pragma unroll
            for (int p = 0; p < 4; p++) wv[p] = w_s[k][nq + 32 * p];
            #pragma unroll
            for (int i = 0; i < 8; i++)
                #pragma unroll
                for (int p = 0; p < 4; p++) acc[i][p] += a[i] * wv[p];
        }
        __syncthreads();
    }
    #pragma unroll
    for (int i = 0; i < 8; i++) {
        const int m = m0 + mq + 8 * i;
        #pragma unroll
        for (int p = 0; p < 4; p++)
            U[(size_t)m * 512 + n0 + nq + 32 * p] = acc[i][p];
    }
}

// ---------------------------------------------------------------------------
// Kernel TR: WaRT[k][j] = W_attn[j][512+k]  (512x512 transpose of right half)
// ---------------------------------------------------------------------------
__global__ __launch_bounds__(256) void k_tr(const float* __restrict__ Wattn,
                                            float* __restrict__ WaRT) {
    const int gt = blockIdx.x * 256 + threadIdx.x;
    for (int f = gt; f < 512 * 512; f += 64 * 256) {
        const int k = f >> 9, j = f & 511;
        WaRT[f] = Wattn[(size_t)j * 1024 + 512 + k];
    }
}

// ---------------------------------------------------------------------------
// Persistent scan kernel: 256 blocks x 256 threads, 3 grid syncs per step.
//  A : gatesT[j][b] = G0[t,b,j] + att.WihA[j] + h.Whh[j]  (8 j-rows/block)
//  B : h,c pointwise (redundant per 8 blocks of b) + 25 scores/block
//  C': softmax (redundant) + att[b, 64-slice] via U and WaRT
// ---------------------------------------------------------------------------
__global__ __launch_bounds__(256) void k_scan(const float* __restrict__ G0,
                                              const float* __restrict__ U,
                                              const float* __restrict__ WaRT,
                                              const float* __restrict__ Wih,
                                              const float* __restrict__ Whh,
                                              const float* __restrict__ src,
                                              const int* __restrict__ lens,
                                              float* __restrict__ gT,
                                              float* __restrict__ hbuf,
                                              float* __restrict__ cbuf,
                                              float* __restrict__ attbuf,
                                              float* __restrict__ scb,
                                              float* __restrict__ h_hist,
                                              float* __restrict__ att_hist,
                                              int* __restrict__ bar) {
    __shared__ float smem[4352];
    const int blk = blockIdx.x, tid = threadIdx.x;
    int ph = 0;

    for (int t = 0; t < T_; t++) {
        // ---------------- Phase A: gates ----------------
        {
            float4* X4 = (float4*)smem;            // [32][33] float4
            const int j0 = blk * 8;
            const int k8 = tid >> 5, b = tid & 31;
            float acc[8] = {};
            for (int ck = 0; ck < 8; ck++) {
                const float* xsrc = (ck < 4) ? (attbuf + (ck * 128)) : (hbuf + (ck - 4) * 128);
                #pragma unroll
                for (int u = 0; u < 4; u++) {
                    const int idx = tid + u * 256;
                    const int bb = idx >> 5, kq = idx & 31;
                    X4[bb * 33 + kq] = *(const float4*)(xsrc + (size_t)bb * 512 + kq * 4);
                }
                __syncthreads();
                #pragma unroll
                for (int kq4 = 0; kq4 < 4; kq4++) {
                    const float4 x = X4[b * 33 + k8 * 4 + kq4];
                    const int kf = (k8 * 4 + kq4) * 4;
                    #pragma unroll
                    for (int r = 0; r < 8; r++) {
                        const float* wr = (ck < 4)
                            ? (Wih + (size_t)(j0 + r) * 1024 + 512 + ck * 128)
                            : (Whh + (size_t)(j0 + r) * 512 + (ck - 4) * 128);
                        const float4 w = *(const float4*)(wr + kf);
                        acc[r] += x.x * w.x + x.y * w.y + x.z * w.z + x.w * w.w;
                    }
                }
                __syncthreads();
            }
            // reduce over k8
            #pragma unroll
            for (int r = 0; r < 8; r++) smem[(r * 32 + b) * 8 + k8] = acc[r];
            __syncthreads();
            {
                const int r = tid >> 5, b2 = tid & 31;
                float g = 0.f;
                #pragma unroll
                for (int k = 0; k < 8; k++) g += smem[(r * 32 + b2) * 8 + k];
                gT[(size_t)(j0 + r) * 32 + b2] =
                    g + G0[((size_t)t * 32 + b2) * G4_ + j0 + r];
            }
        }
        ph++; grid_sync(bar, ph * 256);

        // ---------------- Phase B: pointwise + scores ----------------
        {
            float* h_s = smem;                     // [512]
            const int b = blk >> 3, p = blk & 7;
            #pragma unroll
            for (int uu = 0; uu < 2; uu++) {
                const int u = tid + uu * 256;
                const float gi = gT[(size_t)(u) * 32 + b];
                const float gf = gT[(size_t)(512 + u) * 32 + b];
                const float gg = gT[(size_t)(1024 + u) * 32 + b];
                const float go = gT[(size_t)(1536 + u) * 32 + b];
                const float co = cbuf[(t & 1) * 16384 + b * 512 + u];
                const float cn = sigf(gf) * co + sigf(gi) * tanhf(gg);
                const float hn = sigf(go) * tanhf(cn);
                h_s[u] = hn;
                if (p == 0) {
                    cbuf[((t + 1) & 1) * 16384 + b * 512 + u] = cn;
                    hbuf[b * 512 + u] = hn;
                    h_hist[((size_t)t * 32 + b) * 512 + u] = hn;
                }
            }
            __syncthreads();
            const int w = tid >> 6, lane = tid & 63;
            const int len = lens[b];
            for (int i = w; i < 25; i += 4) {
                const int s = p * 25 + i;
                const float* sr = src + ((size_t)b * S_ + s) * 512;
                const float4 x0 = *(const float4*)(sr + lane * 4);
                const float4 x1 = *(const float4*)(sr + 256 + lane * 4);
                const float4 h0 = *(const float4*)(&h_s[lane * 4]);
                const float4 h1 = *(const float4*)(&h_s[256 + lane * 4]);
                float acc = x0.x * h0.x + x0.y * h0.y + x0.z * h0.z + x0.w * h0.w
                          + x1.x * h1.x + x1.y * h1.y + x1.z * h1.z + x1.w * h1.w;
                #pragma unroll
                for (int m = 1; m < 64; m <<= 1) acc += __shfl_xor(acc, m);
                if (lane == 0) scb[b * 256 + s] = (s < len) ? acc : -INFINITY;
            }
        }
        ph++; grid_sync(bar, ph * 256);

        // ---------------- Phase C': softmax + att slice ----------------
        {
            float* h_s = smem;                     // [512]
            float* al = smem + 512;                // [256]
            float* partial = smem + 768;           // [256]
            const int b = blk >> 3, p = blk & 7;
            h_s[tid] = hbuf[b * 512 + tid];
            h_s[tid + 256] = hbuf[b * 512 + 256 + tid];
            if (tid < 64) {
                const float v0 = scb[b * 256 + tid];
                const float v1 = scb[b * 256 + 64 + tid];
                const float v2 = scb[b * 256 + 128 + tid];
                const float v3 = (tid + 192 < S_) ? scb[b * 256 + 192 + tid] : -INFINITY;
                float m = fmaxf(fmaxf(v0, v1), fmaxf(v2, v3));
                #pragma unroll
                for (int mk = 1; mk < 64; mk <<= 1) m = fmaxf(m, __shfl_xor(m, mk));
                const float e0 = expf(v0 - m), e1 = expf(v1 - m), e2 = expf(v2 - m);
                const float e3 = (tid + 192 < S_) ? expf(v3 - m) : 0.f;
                float sum = (e0 + e1) + (e2 + e3);
                #pragma unroll
                for (int mk = 1; mk < 64; mk <<= 1) sum += __shfl_xor(sum, mk);
                const float inv = 1.f / sum;
                al[tid] = e0 * inv; al[64 + tid] = e1 * inv; al[128 + tid] = e2 * inv;
                if (tid + 192 < S_) al[192 + tid] = e3 * inv;
            }
            __syncthreads();
            const int jl = tid & 63, sg = tid >> 6;
            const int j = p * 64 + jl;
            float acc = 0.f;
            #pragma unroll 2
            for (int s = sg; s < S_; s += 4)
                acc += al[s] * U[((size_t)b * S_ + s) * 512 + j];
            const float* wc = WaRT + j;
            #pragma unroll 4
            for (int k = sg * 128; k < sg * 128 + 128; k++)
                acc += h_s[k] * wc[(size_t)k * 512];
            partial[sg * 64 + jl] = acc;
            __syncthreads();
            if (tid < 64) {
                const float tot = partial[tid] + partial[64 + tid]
                                + partial[128 + tid] + partial[192 + tid];
                const float a = tanhf(tot);
                attbuf[b * 512 + p * 64 + tid] = a;
                att_hist[((size_t)t * 32 + b) * 512 + p * 64 + tid] = a;
            }
        }
        ph++; grid_sync(bar, ph * 256);
    }
}

// ---------------------------------------------------------------------------
// Kernel DEC: decs = tanh([emb | h_hist | att_hist] @ Wgen^T + bgen)
// M=1024, N=512, K=1536 (3 segments of 512)
// ---------------------------------------------------------------------------
__global__ __launch_bounds__(256) void k_dec(const int* __restrict__ tgt_in,
                                             const float* __restrict__ emb,
                                             const float* __restrict__ h_hist,
                                             const float* __restrict__ att_hist,
                                             const float* __restrict__ Wgen,
                                             const float* __restrict__ bgen,
                                             float* __restrict__ decs) {
    __shared__ float a_s[32][66];
    __shared__ float w_s[32][130];
    const int tid = threadIdx.x;
    const int m0 = blockIdx.x * 64, n0 = blockIdx.y * 128;
    const int mq = tid >> 5, nq = tid & 31;
    float acc[8][4] = {};
    for (int k0 = 0; k0 < 1536; k0 += 32) {
        {
            const int mm = tid >> 2, kq = tid & 3, kk = kq * 8;
            const int m = m0 + mm;
            const float* row;
            if (k0 < 512)       row = emb + (size_t)tgt_in[m] * E_ + k0;
            else if (k0 < 1024) row = h_hist + (size_t)m * 512 + (k0 - 512);
            else                row = att_hist + (size_t)m * 512 + (k0 - 1024);
            row += kk;
            float4 v0 = *(const float4*)(row);
            float4 v1 = *(const float4*)(row + 4);
            a_s[kk + 0][mm] = v0.x; a_s[kk + 1][mm] = v0.y;
            a_s[kk + 2][mm] = v0.z; a_s[kk + 3][mm] = v0.w;
            a_s[kk + 4][mm] = v1.x; a_s[kk + 5][mm] = v1.y;
            a_s[kk + 6][mm] = v1.z; a_s[kk + 7][mm] = v1.w;
        }
        {
            const int nn = tid >> 1, kq = tid & 1, kk = kq * 16;
            const float* row = Wgen + (size_t)(n0 + nn) * 1536 + k0 + kk;
            #pragma unroll
            for (int u = 0; u < 4; u++) {
                float4 v = *(const float4*)(row + u * 4);
                w_s[kk + u * 4 + 0][nn] = v.x; w_s[kk + u * 4 + 1][nn] = v.y;
                w_s[kk + u * 4 + 2][nn] = v.z; w_s[kk + u * 4 + 3][nn] = v.w;
            }
        }
        __syncthreads();
        for (int k = 0; k < 32; k++) {
            float a[8], wv[4];
            #pragma unroll
            for (int i = 0; i < 8; i++) a[i] = a_s[k][mq + 8 * i];
            #pragma unroll
            for (int p = 0; p < 4; p++) wv[p] = w_s[k][nq + 32 * p];
            #pragma unroll
            for (int i = 0; i < 8; i++)
                #pragma unroll
                for (int p = 0; p < 4; p++) acc[i][p] += a[i] * wv[p];
        }
        __syncthreads();
    }
    #pragma unroll
    for (int i = 0; i < 8; i++) {
        const int m = m0 + mq + 8 * i;
        #pragma unroll
        for (int p = 0; p < 4; p++) {
            const int n = n0 + nq + 32 * p;
            decs[(size_t)m * 512 + n] = tanhf(acc[i][p] + bgen[n]);
        }
    }
}

// ---------------------------------------------------------------------------
// Kernel C: readout GEMM partials (unchanged from round 1).
// ---------------------------------------------------------------------------
__global__ __launch_bounds__(256) void k_read(const float* __restrict__ decs,
                                              const float* __restrict__ Wread,
                                              const int* __restrict__ tgt_out,
                                              float4* __restrict__ part,
                                              float* __restrict__ tgt_logit) {
    __shared__ float a_s[32][66];
    __shared__ float w_s[32][258];
    const int tid = threadIdx.x;
    const int m0 = blockIdx.x * 64;
    const int ch = blockIdx.y;
    const int n0 = ch * 256;
    const int mq = tid >> 5, nq = tid & 31;
    float acc[8][8] = {};
    for (int k0 = 0; k0 < 512; k0 += 32) {
        {
            const int mm = tid >> 2, kq = tid & 3, kk = kq * 8;
            const float* row = decs + (size_t)(m0 + mm) * H_ + k0 + kk;
            float4 v0 = *(const float4*)(row);
            float4 v1 = *(const float4*)(row + 4);
            a_s[kk + 0][mm] = v0.x; a_s[kk + 1][mm] = v0.y;
            a_s[kk + 2][mm] = v0.z; a_s[kk + 3][mm] = v0.w;
            a_s[kk + 4][mm] = v1.x; a_s[kk + 5][mm] = v1.y;
            a_s[kk + 6][mm] = v1.z; a_s[kk + 7][mm] = v1.w;
        }
        {
            const int nn = tid;
            const int n = n0 + nn;
            if (n < V_) {
                const float* row = Wread + (size_t)n * H_ + k0;
                #pragma unroll
                for (int u = 0; u < 8; u++) {
                    float4 v = *(const float4*)(row + u * 4);
                    w_s[u * 4 + 0][nn] = v.x; w_s[u * 4 + 1][nn] = v.y;
                    w_s[u * 4 + 2][nn] = v.z; w_s[u * 4 + 3][nn] = v.w;
                }
            } else {
                #pragma unroll
                for (int u = 0; u < 32; u++) w_s[u][nn] = 0.f;
            }
        }
        __syncthreads();
        for (int k = 0; k < 32; k++) {
            float a[8], wv[8];
            #pragma unroll
            for (int i = 0; i < 8; i++) a[i] = a_s[k][mq + 8 * i];
            #pragma unroll
            for (int j = 0; j < 8; j++) wv[j] = w_s[k][nq + 32 * j];
            #pragma unroll
            for (int i = 0; i < 8; i++)
                #pragma unroll
                for (int j = 0; j < 8; j++) acc[i][j] += a[i] * wv[j];
        }
        __syncthreads();
    }
    #pragma unroll
    for (int i = 0; i < 8; i++) {
        const int m = m0 + mq + 8 * i;
        float bv = -INFINITY; int bi = 0x7fffffff;
        #pragma unroll
        for (int j = 0; j < 8; j++) {
            const int n = n0 + nq + 32 * j;
            const float v = (n < V_) ? acc[i][j] : -INFINITY;
            if (v > bv || (v == bv && n < bi)) { bv = v; bi = n; }
        }
        #pragma unroll
        for (int mk = 1; mk < 32; mk <<= 1) {
            const float ov = __shfl_xor(bv, mk);
            const int oi = __shfl_xor(bi, mk);
            if (ov > bv || (ov == bv && oi < bi)) { bv = ov; bi = oi; }
        }
        float se = 0.f;
        #pragma unroll
        for (int j = 0; j < 8; j++) {
            const int n = n0 + nq + 32 * j;
            se += (n < V_) ? expf(acc[i][j] - bv) : 0.f;
        }
        #pragma unroll
        for (int mk = 1; mk < 32; mk <<= 1) se += __shfl_xor(se, mk);
        if (nq == 0) part[(size_t)m * NCH + ch] = make_float4(bv, se, __int_as_float(bi), 0.f);
        const int ct = tgt_out[m];
        const int rel = ct - n0;
        if (rel >= 0 && rel < 256 && (rel & 31) == nq) {
            #pragma unroll
            for (int j = 0; j < 8; j++)
                if (rel == nq + 32 * j) tgt_logit[m] = acc[i][j];
        }
    }
}

// ---------------------------------------------------------------------------
// Kernel D: merge chunk partials per row -> loss + argmax (unchanged).
// ---------------------------------------------------------------------------
__global__ __launch_bounds__(256) void k_merge(const float4* __restrict__ part,
                                               const float* __restrict__ tgt_logit,
                                               const int* __restrict__ tgt_out,
                                               float* __restrict__ out) {
    const int tid = threadIdx.x;
    const int w = tid >> 6, lane = tid & 63;
    const int row = blockIdx.x * 4 + w;
    float bm = -INFINITY; int bi = 0x7fffffff;
    for (int ch = lane; ch < NCH; ch += 64) {
        const float4 p = part[(size_t)row * NCH + ch];
        const int pi = __float_as_int(p.z);
        if (p.x > bm || (p.x == bm && pi < bi)) { bm = p.x; bi = pi; }
    }
    #pragma unroll
    for (int mk = 1; mk < 64; mk <<= 1) {
        const float ov = __shfl_xor(bm, mk);
        const int oi = __shfl_xor(bi, mk);
        if (ov > bm || (ov == bm && oi < bi)) { bm = ov; bi = oi; }
    }
    float sum = 0.f;
    for (int ch = lane; ch < NCH; ch += 64) {
        const float4 p = part[(size_t)row * NCH + ch];
        sum += p.y * expf(p.x - bm);
    }
    #pragma unroll
    for (int mk = 1; mk < 64; mk <<= 1) sum += __shfl_xor(sum, mk);
    if (lane == 0) {
        const float lse = bm + logf(sum);
        const int tg = tgt_out[row];
        const float loss = (tg != 0) ? (lse - tgt_logit[row]) : 0.f;
        out[row] = loss;
        out[1024 + row] = (float)bi;
    }
}

// ---------------------------------------------------------------------------
extern "C" void kernel_launch(void* const* d_in, const int* in_sizes, int n_in,
                              void* d_out, int out_size, void* d_ws, size_t ws_size,
                              hipStream_t stream) {
    const int* tgt_in = (const int*)d_in[0];
    const int* tgt_out = (const int*)d_in[1];
    const int* src_lens = (const int*)d_in[2];
    const float* src = (const float*)d_in[3];
    const float* last_state = (const float*)d_in[4];
    const float* last_cell = (const float*)d_in[5];
    const float* emb = (const float*)d_in[6];
    const float* Wih = (const float*)d_in[7];
    const float* Whh = (const float*)d_in[8];
    const float* bih = (const float*)d_in[9];
    const float* bhh = (const float*)d_in[10];
    const float* Wattn = (const float*)d_in[11];
    const float* Wgen = (const float*)d_in[12];
    const float* bgen = (const float*)d_in[13];
    const float* Wread = (const float*)d_in[14];
    float* out = (float*)d_out;

    float* ws = (float*)d_ws;
    float* G0       = ws;                   // 2,097,152
    float* U        = G0 + 2097152;         // 3,276,800
    float* WaRT     = U + 3276800;          // 262,144
    float* decs     = WaRT + 262144;        // 524,288
    float* h_hist   = decs + 524288;        // 524,288
    float* att_hist = h_hist + 524288;      // 524,288
    float* hbuf     = att_hist + 524288;    // 16,384
    float* cbuf     = hbuf + 16384;         // 32,768 (double buffer)
    float* attbuf   = cbuf + 32768;         // 16,384
    float* gT       = attbuf + 16384;       // 65,536
    float* scb      = gT + 65536;           // 8,192
    float4* part    = (float4*)(scb + 8192);// 200,704 float4
    float* tgtl     = ((float*)part) + 802816; // 1,024
    int* bar        = (int*)(tgtl + 1024);

    hipMemsetAsync(bar, 0, 256, stream);
    hipMemsetAsync(attbuf, 0, (size_t)B_ * H_ * 4, stream);
    hipMemcpyAsync(hbuf, last_state, (size_t)B_ * H_ * 4, hipMemcpyDeviceToDevice, stream);
    hipMemcpyAsync(cbuf, last_cell, (size_t)B_ * H_ * 4, hipMemcpyDeviceToDevice, stream);

    k_g0<<<dim3(16, 16), 256, 0, stream>>>(tgt_in, emb, Wih, bih, bhh, G0);
    k_u<<<dim3(100, 4), 256, 0, stream>>>(src, Wattn, U);
    k_tr<<<64, 256, 0, stream>>>(Wattn, WaRT);

    k_scan<<<256, 256, 0, stream>>>(G0, U, WaRT, Wih, Whh, src, src_lens,
                                    gT, hbuf, cbuf, attbuf, scb, h_hist, att_hist, bar);

    k_dec<<<dim3(16, 4), 256, 0, stream>>>(tgt_in, emb, h_hist, att_hist, Wgen, bgen, decs);
    k_read<<<dim3(16, NCH), 256, 0, stream>>>(decs, Wread, tgt_out, part, tgtl);
    k_merge<<<256, 256, 0, stream>>>(part, tgtl, tgt_out, out);
}